// Round 2
// baseline (119.162 us; speedup 1.0000x reference)
//
#include <hip/hip_runtime.h>
#include <math.h>

#define HWP 3136   // 56*56
#define W56 56
#define TPP 392    // 8-wide tasks per plane: 7 per row * 56 rows

// ---- weight pre-quantization: wq = sign(w) * 2^clip(rint(log2|w|), -14, 0) ----
__global__ __launch_bounds__(256) void quant_weights(const float* __restrict__ wgt,
                                                     float* __restrict__ wq, int n) {
    int i = blockIdx.x * 256 + threadIdx.x;
    if (i < n) {
        float v  = wgt[i];
        float s  = (v > 0.f) ? 1.f : ((v < 0.f) ? -1.f : 0.f);
        float sh = rintf(log2f(fabsf(v) + 1e-45f));   // rintf = round-half-even (jnp.round)
        sh = fminf(fmaxf(sh, -14.f), 0.f);
        wq[i] = s * exp2f(sh);
    }
}

// round_to_fixed: floor to 2^-16 grid. (clip to +/-2^15 is an exact no-op for
// N(0,1) inputs, |x| < 8 << 32768, identical in the reference too.)
__device__ __forceinline__ float qfix(float v) {
    return floorf(v * 65536.f) * (1.f / 65536.f);
}

// One thread computes 8 consecutive outputs of one row. No LDS, no barriers:
// the 56x56 plane (12.5 KB) is L1-resident, halo re-reads hit cache.
__global__ __launch_bounds__(256) void dwconv3x3_direct(
    const float* __restrict__ x, const float* __restrict__ wq,
    float* __restrict__ out, int C, int nTasks, int preq)
{
    int t = blockIdx.x * 256 + threadIdx.x;
    if (t >= nTasks) return;
    int plane = t / TPP;
    int rem   = t - plane * TPP;
    int h     = rem / 7;
    int w8    = rem - h * 7;
    int wc    = w8 * 8;

    const float* xp = x + (size_t)plane * HWP;
    const float* wp = wq + (size_t)(plane % C) * 9;

    // weights (precomputed path: plain loads, wave-mostly-uniform -> broadcast)
    float w9[9];
    #pragma unroll
    for (int k = 0; k < 9; ++k) w9[k] = wp[k];
    if (!preq) {  // fallback if d_ws was too small: quantize inline
        #pragma unroll
        for (int k = 0; k < 9; ++k) {
            float v  = w9[k];
            float s  = (v > 0.f) ? 1.f : ((v < 0.f) ? -1.f : 0.f);
            float sh = rintf(log2f(fabsf(v) + 1e-45f));
            sh = fminf(fmaxf(sh, -14.f), 0.f);
            w9[k] = s * exp2f(sh);
        }
    }

    float acc[8];
    #pragma unroll
    for (int j = 0; j < 8; ++j) acc[j] = 0.f;

    #pragma unroll
    for (int dh = 0; dh < 3; ++dh) {
        int  r     = h + dh - 1;
        bool valid = (r >= 0) && (r < 56);
        int  rc    = min(max(r, 0), 55);          // clamped row: always in-bounds
        const float* row = xp + rc * W56 + wc;

        float4 m0 = *(const float4*)(row);
        float4 m1 = *(const float4*)(row + 4);
        float left  = (wc > 0)      ? row[-1] : 0.f;   // exec-masked load at edges
        float right = (wc + 8 < 56) ? row[8]  : 0.f;

        float v[10];
        v[0] = qfix(left);
        v[1] = qfix(m0.x); v[2] = qfix(m0.y); v[3] = qfix(m0.z); v[4] = qfix(m0.w);
        v[5] = qfix(m1.x); v[6] = qfix(m1.y); v[7] = qfix(m1.z); v[8] = qfix(m1.w);
        v[9] = qfix(right);

        // invalid (out-of-image) row: zero the 3 row-weights instead of 10 values
        float a = valid ? w9[dh * 3 + 0] : 0.f;
        float b = valid ? w9[dh * 3 + 1] : 0.f;
        float c = valid ? w9[dh * 3 + 2] : 0.f;

        #pragma unroll
        for (int j = 0; j < 8; ++j)
            acc[j] = fmaf(a, v[j], fmaf(b, v[j + 1], fmaf(c, v[j + 2], acc[j])));
    }

    float* op = out + (size_t)plane * HWP + h * W56 + wc;
    *(float4*)(op)     = make_float4(acc[0], acc[1], acc[2], acc[3]);
    *(float4*)(op + 4) = make_float4(acc[4], acc[5], acc[6], acc[7]);
}

extern "C" void kernel_launch(void* const* d_in, const int* in_sizes, int n_in,
                              void* d_out, int out_size, void* d_ws, size_t ws_size,
                              hipStream_t stream) {
    const float* x   = (const float*)d_in[0];
    const float* wgt = (const float*)d_in[1];
    float* out       = (float*)d_out;

    const int planes = out_size / HWP;       // B*C = 12288
    const int nW     = in_sizes[1];          // C*9 = 3456
    const int C      = nW / 9;
    const int nTasks = planes * TPP;         // 4,816,896

    int preq = (ws_size >= (size_t)nW * sizeof(float)) ? 1 : 0;
    const float* wqp = wgt;
    if (preq) {
        float* wqbuf = (float*)d_ws;
        quant_weights<<<(nW + 255) / 256, 256, 0, stream>>>(wgt, wqbuf, nW);
        wqp = wqbuf;
    }

    dwconv3x3_direct<<<(nTasks + 255) / 256, 256, 0, stream>>>(
        x, wqp, out, C, nTasks, preq);
}

// Round 3
// 90.114 us; speedup vs baseline: 1.3224x; 1.3224x over previous
//
#include <hip/hip_runtime.h>
#include <math.h>

#define HWP 3136   // 56*56
#define W56 56

// ---- weight pre-quantization: wq = sign(w) * 2^clip(rint(log2|w|), -14, 0) ----
__global__ __launch_bounds__(256) void quant_weights(const float* __restrict__ wgt,
                                                     float* __restrict__ wq, int n) {
    int i = blockIdx.x * 256 + threadIdx.x;
    if (i < n) {
        float v  = wgt[i];
        float s  = (v > 0.f) ? 1.f : ((v < 0.f) ? -1.f : 0.f);
        float sh = rintf(log2f(fabsf(v) + 1e-45f));   // rintf = round-half-even (jnp.round)
        sh = fminf(fmaxf(sh, -14.f), 0.f);
        wq[i] = s * exp2f(sh);
    }
}

// round_to_fixed: floor to 2^-16 grid. (clip to +/-2^15 is an exact no-op for
// N(0,1)-scaled inputs, |x| << 32768 — identical in the reference.)
__device__ __forceinline__ float qfix(float v) {
    return floorf(v * 65536.f) * (1.f / 65536.f);
}

// One WAVE per (b,c) plane. Lane = column (56 of 64 active). Roll 3 quantized
// rows through registers; neighbors via shuffles; every input byte read once.
__global__ __launch_bounds__(256) void dwconv3x3_rows(
    const float* __restrict__ x, const float* __restrict__ wq,
    float* __restrict__ out, int C, int planes, int preq)
{
    const int gwave = (int)((blockIdx.x * 256 + threadIdx.x) >> 6);
    const int lane  = threadIdx.x & 63;
    if (gwave >= planes) return;

    const float* __restrict__ xp = x + (size_t)gwave * HWP;
    float*       __restrict__ op = out + (size_t)gwave * HWP;
    const float* wp = wq + (size_t)(gwave % C) * 9;

    float w9[9];
    #pragma unroll
    for (int k = 0; k < 9; ++k) w9[k] = wp[k];
    if (!preq) {
        #pragma unroll
        for (int k = 0; k < 9; ++k) {
            float v  = w9[k];
            float s  = (v > 0.f) ? 1.f : ((v < 0.f) ? -1.f : 0.f);
            float sh = rintf(log2f(fabsf(v) + 1e-45f));
            sh = fminf(fmaxf(sh, -14.f), 0.f);
            w9[k] = s * exp2f(sh);
        }
    }
    const float w00 = w9[0], w01 = w9[1], w02 = w9[2];
    const float w10 = w9[3], w11 = w9[4], w12 = w9[5];
    const float w20 = w9[6], w21 = w9[7], w22 = w9[8];

    const bool active = lane < W56;

    // rolling rows: a = h-1, b = h, c = h+1 (L = left-shifted, C = center, R = right)
    float aL = 0.f, aC = 0.f, aR = 0.f;
    float bL, bC, bR, cL, cC, cR;

    float rawB = active ? xp[lane] : 0.f;              // row 0
    float rawC = active ? xp[W56 + lane] : 0.f;        // row 1
    {
        float v = qfix(rawB);
        float l = __shfl_up(v, 1);  if (lane == 0) l = 0.f;   // col -1 pad
        float r = __shfl_down(v, 1);                          // lane55 <- lane56 (=0) pad
        bL = l; bC = v; bR = r;
    }

    #pragma unroll 4
    for (int h = 0; h < W56; ++h) {
        // issue load of row h+2 early (2-ahead prefetch)
        float rawN = 0.f;
        if (h + 2 < W56) rawN = active ? xp[(h + 2) * W56 + lane] : 0.f;

        // build row h+1 triple from rawC (bottom pad at h=55)
        if (h + 1 < W56) {
            float v = qfix(rawC);
            float l = __shfl_up(v, 1);  if (lane == 0) l = 0.f;
            float r = __shfl_down(v, 1);
            cL = l; cC = v; cR = r;
        } else {
            cL = 0.f; cC = 0.f; cR = 0.f;
        }

        float acc =
            fmaf(w00, aL, fmaf(w01, aC, fmaf(w02, aR,
            fmaf(w10, bL, fmaf(w11, bC, fmaf(w12, bR,
            fmaf(w20, cL, fmaf(w21, cC, w22 * cR))))))));

        if (active) op[h * W56 + lane] = acc;

        aL = bL; aC = bC; aR = bR;
        bL = cL; bC = cC; bR = cR;
        rawC = rawN;
    }
}

extern "C" void kernel_launch(void* const* d_in, const int* in_sizes, int n_in,
                              void* d_out, int out_size, void* d_ws, size_t ws_size,
                              hipStream_t stream) {
    const float* x   = (const float*)d_in[0];
    const float* wgt = (const float*)d_in[1];
    float* out       = (float*)d_out;

    const int planes = out_size / HWP;       // B*C = 12288
    const int nW     = in_sizes[1];          // C*9 = 3456
    const int C      = nW / 9;

    int preq = (ws_size >= (size_t)nW * sizeof(float)) ? 1 : 0;
    const float* wqp = wgt;
    if (preq) {
        float* wqbuf = (float*)d_ws;
        quant_weights<<<(nW + 255) / 256, 256, 0, stream>>>(wgt, wqbuf, nW);
        wqp = wqbuf;
    }

    const int nThreads = planes * 64;        // one wave per plane
    dwconv3x3_rows<<<(nThreads + 255) / 256, 256, 0, stream>>>(
        x, wqp, out, C, planes, preq);
}

// Round 4
// 84.277 us; speedup vs baseline: 1.4139x; 1.0693x over previous
//
#include <hip/hip_runtime.h>
#include <math.h>

#define HWP   3136   // 56*56
#define W56   56
#define PITCH 64     // LDS row pitch in floats (interior at column offset +4)
#define NF4   784    // float4 tasks per plane (14 per row * 56 rows)

// round_to_fixed: floor to 2^-16 grid. (clip to +/-2^15 is an exact no-op for
// N(0,1) inputs, |x| << 32768 — identical in the reference.)
__device__ __forceinline__ float qfix(float v) {
    return floorf(v * 65536.f) * (1.f / 65536.f);
}

// Block = 256 threads = one (b,c) plane. LDS tile [58][64], input row h at tile
// row h+1, input col j at tile col j+4. All LDS access 8/16B-aligned ->
// conflict-free (stage: b128 stride-4; compute: b64/b128 stride-4 = 2-way, free).
__global__ __launch_bounds__(256) void dwconv3x3_lds(
    const float* __restrict__ x, const float* __restrict__ wgt,
    float* __restrict__ out, int C)
{
    __shared__ float tile[58 * PITCH];   // 14848 B -> 8 blocks/CU (wave-capped), 100% occ
    __shared__ float wq[9];

    const int tid   = threadIdx.x;
    const int plane = blockIdx.x;

    // targeted zero padding: top/bottom pad rows + left(col3)/right(col60) pads
    if (tid < 64) {
        tile[tid] = 0.f;                          // tile row 0 (input row -1)
    } else if (tid < 128) {
        tile[57 * PITCH + (tid - 64)] = 0.f;      // tile row 57 (input row 56)
    } else if (tid < 240) {
        int k = tid - 128;                        // 112 words: rows 1..56 x {3,60}
        int r = 1 + (k >> 1);
        tile[r * PITCH + ((k & 1) ? 60 : 3)] = 0.f;
    }

    // quantize the 9 depthwise weights: sign(w) * 2^clip(rint(log2|w|), -14, 0)
    if (tid < 9) {
        float v  = wgt[(plane % C) * 9 + tid];
        float s  = (v > 0.f) ? 1.f : ((v < 0.f) ? -1.f : 0.f);
        float sh = rintf(log2f(fabsf(v) + 1e-45f));   // round-half-even = jnp.round
        sh = fminf(fmaxf(sh, -14.f), 0.f);
        wq[tid] = s * exp2f(sh);
    }

    // stage: quantize + aligned ds_write_b128 (conflict-free)
    const float4* __restrict__ xp = (const float4*)(x + (size_t)plane * HWP);
    #pragma unroll
    for (int it = 0; it < 4; ++it) {
        int i = tid + it * 256;
        if (i < NF4) {
            float4 v = xp[i];
            v.x = qfix(v.x); v.y = qfix(v.y); v.z = qfix(v.z); v.w = qfix(v.w);
            int h   = i / 14;            // 14 float4 per row
            int wc4 = i - h * 14;
            *(float4*)&tile[(h + 1) * PITCH + wc4 * 4 + 4] = v;
        }
    }
    __syncthreads();

    const float w00 = wq[0], w01 = wq[1], w02 = wq[2];
    const float w10 = wq[3], w11 = wq[4], w12 = wq[5];
    const float w20 = wq[6], w21 = wq[7], w22 = wq[8];

    // compute: per row read b64(edge-left) + b128(center) + b64(edge-right), all aligned
    float* __restrict__ op = out + (size_t)plane * HWP;
    #pragma unroll
    for (int it = 0; it < 4; ++it) {
        int j = tid + it * 256;
        if (j < NF4) {
            int h  = j / 14;
            int wc = (j - h * 14) * 4;
            int b0 = h * PITCH + wc;     // tile rows h..h+2 = input rows h-1..h+1
            float4 o = make_float4(0.f, 0.f, 0.f, 0.f);
            #pragma unroll
            for (int dh = 0; dh < 3; ++dh) {
                const float* rp = &tile[b0 + dh * PITCH];
                float2 L = *(const float2*)(rp + 2);   // L.y = input col wc-1
                float4 q = *(const float4*)(rp + 4);   // cols wc..wc+3
                float2 R = *(const float2*)(rp + 8);   // R.x = col wc+4
                float a, b, c;
                if (dh == 0)      { a = w00; b = w01; c = w02; }
                else if (dh == 1) { a = w10; b = w11; c = w12; }
                else              { a = w20; b = w21; c = w22; }
                o.x = fmaf(a, L.y, fmaf(b, q.x, fmaf(c, q.y, o.x)));
                o.y = fmaf(a, q.x, fmaf(b, q.y, fmaf(c, q.z, o.y)));
                o.z = fmaf(a, q.y, fmaf(b, q.z, fmaf(c, q.w, o.z)));
                o.w = fmaf(a, q.z, fmaf(b, q.w, fmaf(c, R.x, o.w)));
            }
            *(float4*)(op + h * W56 + wc) = o;
        }
    }
}

extern "C" void kernel_launch(void* const* d_in, const int* in_sizes, int n_in,
                              void* d_out, int out_size, void* d_ws, size_t ws_size,
                              hipStream_t stream) {
    const float* x   = (const float*)d_in[0];
    const float* wgt = (const float*)d_in[1];
    float* out       = (float*)d_out;

    const int planes = out_size / HWP;    // B*C = 12288
    const int C      = in_sizes[1] / 9;   // 384

    dwconv3x3_lds<<<planes, 256, 0, stream>>>(x, wgt, out, C);
}

// Round 5
// 73.141 us; speedup vs baseline: 1.6292x; 1.1522x over previous
//
#include <hip/hip_runtime.h>
#include <math.h>

#define HWP   3136   // 56*56
#define W56   56
#define PITCH 68     // 68 % 32 = 4 -> per-row bank-group rotation (anti-conflict), rows stay 16B-aligned
#define TPP   392    // 8-wide tasks per plane: 7 per row * 56 rows

// round_to_fixed: floor to 2^-16 grid. (clip to +/-2^15 is an exact no-op for
// N(0,1) inputs, |x| << 32768 — identical in the reference.)
__device__ __forceinline__ float qfix(float v) {
    return floorf(v * 65536.f) * (1.f / 65536.f);
}

// Block = 256 threads = one (b,c) plane. LDS tile [58][68]; input row h at tile
// row h+1, input col j at tile col j+4. PITCH=68 rotates bank groups by 1 per
// row ((68*r+c)/4 mod 8 = (r + c/4) mod 8), breaking the row-aliasing that made
// PITCH=64 an 8-way conflict. All accesses 8/16B-aligned vector ops.
__global__ __launch_bounds__(256) void dwconv3x3_lds(
    const float* __restrict__ x, const float* __restrict__ wgt,
    float* __restrict__ out, int C)
{
    __shared__ float tile[58 * PITCH];   // 15776 B -> 8 blocks/CU (wave-capped)
    __shared__ float wq[9];

    const int tid   = threadIdx.x;
    const int plane = blockIdx.x;

    // targeted zero padding: top/bottom pad rows + left(col3)/right(col60) pads
    if (tid < 68) {
        tile[tid] = 0.f;                          // tile row 0 (input row -1)
    } else if (tid < 136) {
        tile[57 * PITCH + (tid - 68)] = 0.f;      // tile row 57 (input row 56)
    } else if (tid < 248) {
        int k = tid - 136;                        // 112 words: rows 1..56 x {3,60}
        int r = 1 + (k >> 1);
        tile[r * PITCH + ((k & 1) ? 60 : 3)] = 0.f;
    }

    // quantize the 9 depthwise weights: sign(w) * 2^clip(rint(log2|w|), -14, 0)
    if (tid < 9) {
        float v  = wgt[(plane % C) * 9 + tid];
        float s  = (v > 0.f) ? 1.f : ((v < 0.f) ? -1.f : 0.f);
        float sh = rintf(log2f(fabsf(v) + 1e-45f));   // round-half-even = jnp.round
        sh = fminf(fmaxf(sh, -14.f), 0.f);
        wq[tid] = s * exp2f(sh);
    }

    // stage: 8 floats/thread (32B/lane global), quantize, 2x aligned ds_write_b128
    const float* __restrict__ xp = x + (size_t)plane * HWP;
    #pragma unroll
    for (int it = 0; it < 2; ++it) {
        int j = tid + it * 256;
        if (j < TPP) {
            int h  = j / 7;
            int w8 = j - h * 7;
            const float* src = xp + h * W56 + w8 * 8;
            float4 a = *(const float4*)(src);
            float4 b = *(const float4*)(src + 4);
            a.x = qfix(a.x); a.y = qfix(a.y); a.z = qfix(a.z); a.w = qfix(a.w);
            b.x = qfix(b.x); b.y = qfix(b.y); b.z = qfix(b.z); b.w = qfix(b.w);
            float* dst = &tile[(h + 1) * PITCH + w8 * 8 + 4];
            *(float4*)(dst)     = a;
            *(float4*)(dst + 4) = b;
        }
    }
    __syncthreads();

    const float w00 = wq[0], w01 = wq[1], w02 = wq[2];
    const float w10 = wq[3], w11 = wq[4], w12 = wq[5];
    const float w20 = wq[6], w21 = wq[7], w22 = wq[8];

    // compute: 8 outputs/thread; per row f2+f4+f4+f2 covers tile cols wc+2..wc+13
    float* __restrict__ op = out + (size_t)plane * HWP;
    #pragma unroll
    for (int it = 0; it < 2; ++it) {
        int j = tid + it * 256;
        if (j < TPP) {
            int h  = j / 7;
            int wc = (j - h * 7) * 8;
            float o0 = 0.f, o1 = 0.f, o2 = 0.f, o3 = 0.f;
            float o4 = 0.f, o5 = 0.f, o6 = 0.f, o7 = 0.f;
            #pragma unroll
            for (int dh = 0; dh < 3; ++dh) {
                const float* rp = &tile[(h + dh) * PITCH + wc];
                float2 L  = *(const float2*)(rp + 2);    // L.y  = input col wc-1
                float4 c0 = *(const float4*)(rp + 4);    // cols wc..wc+3
                float4 c1 = *(const float4*)(rp + 8);    // cols wc+4..wc+7
                float2 R  = *(const float2*)(rp + 12);   // R.x  = input col wc+8
                float a, b, c;
                if (dh == 0)      { a = w00; b = w01; c = w02; }
                else if (dh == 1) { a = w10; b = w11; c = w12; }
                else              { a = w20; b = w21; c = w22; }
                o0 = fmaf(a, L.y,  fmaf(b, c0.x, fmaf(c, c0.y, o0)));
                o1 = fmaf(a, c0.x, fmaf(b, c0.y, fmaf(c, c0.z, o1)));
                o2 = fmaf(a, c0.y, fmaf(b, c0.z, fmaf(c, c0.w, o2)));
                o3 = fmaf(a, c0.z, fmaf(b, c0.w, fmaf(c, c1.x, o3)));
                o4 = fmaf(a, c0.w, fmaf(b, c1.x, fmaf(c, c1.y, o4)));
                o5 = fmaf(a, c1.x, fmaf(b, c1.y, fmaf(c, c1.z, o5)));
                o6 = fmaf(a, c1.y, fmaf(b, c1.z, fmaf(c, c1.w, o6)));
                o7 = fmaf(a, c1.z, fmaf(b, c1.w, fmaf(c, R.x,  o7)));
            }
            float* dst = op + h * W56 + wc;
            *(float4*)(dst)     = make_float4(o0, o1, o2, o3);
            *(float4*)(dst + 4) = make_float4(o4, o5, o6, o7);
        }
    }
}

extern "C" void kernel_launch(void* const* d_in, const int* in_sizes, int n_in,
                              void* d_out, int out_size, void* d_ws, size_t ws_size,
                              hipStream_t stream) {
    const float* x   = (const float*)d_in[0];
    const float* wgt = (const float*)d_in[1];
    float* out       = (float*)d_out;

    const int planes = out_size / HWP;    // B*C = 12288
    const int C      = in_sizes[1] / 9;   // 384

    dwconv3x3_lds<<<planes, 256, 0, stream>>>(x, wgt, out, C);
}